// Round 1
// baseline (509.418 us; speedup 1.0000x reference)
//
#include <hip/hip_runtime.h>
#include <hip/hip_bf16.h>
#include <math.h>

#define B_ 4
#define T_ 2048
#define D_ 1024
#define F_ 2048
#define E_ 8
#define NT (B_ * T_)          // 8192 tokens
#define NS (NT * 2)           // 16384 routed assignments (K=2)
#define CAP (NS + E_ * 256)   // 18432 slots: 256-aligned per-expert segments always fit

typedef __attribute__((ext_vector_type(8))) short short8;
typedef __attribute__((ext_vector_type(4))) float floatx4;

static __device__ __forceinline__ unsigned short f2bf(float f) {
  union { float f; unsigned u; } a; a.f = f;
  unsigned r = a.u + 0x7fffu + ((a.u >> 16) & 1u);  // RNE
  return (unsigned short)(r >> 16);
}

static __device__ __forceinline__ float bf2f(unsigned u) {
  union { unsigned u; float f; } a; a.u = u << 16; return a.f;
}

static __device__ __forceinline__ void gld16(const unsigned short* g, unsigned short* l) {
  __builtin_amdgcn_global_load_lds(
      (const __attribute__((address_space(1))) void*)g,
      (__attribute__((address_space(3))) void*)l, 16, 0, 0);
}

// Branchless GELU: Abramowitz-Stegun 7.1.26 erf (|err| < 1.5e-7), hw exp2/rcp.
static __device__ __forceinline__ float gelu_f(float v) {
  float ax = fabsf(v) * 0.70710678118654752f;
  float t = __builtin_amdgcn_rcpf(1.f + 0.3275911f * ax);
  float e = __builtin_amdgcn_exp2f(-ax * ax * 1.44269504088896f);  // exp(-ax^2)
  float p = t * (0.254829592f +
            t * (-0.284496736f +
            t * (1.421413741f +
            t * (-1.453152027f +
            t * 1.061405429f))));
  float er = 1.f - p * e;
  er = copysignf(er, v);
  return 0.5f * v * (1.f + er);
}

// ---- weight transpose + fp32->bf16 convert: in [E][R][C] -> out [E][C][R] ----
__global__ void transpose_cvt(const float* __restrict__ in, unsigned short* __restrict__ out,
                              int R, int C) {
  __shared__ float tile[32][33];
  int e = blockIdx.z;
  const float* inp = in + (size_t)e * R * C;
  unsigned short* outp = out + (size_t)e * R * C;
  int c0 = blockIdx.x * 32, r0 = blockIdx.y * 32;
  int tx = threadIdx.x, ty = threadIdx.y;
#pragma unroll
  for (int j = 0; j < 4; j++)
    tile[ty + 8 * j][tx] = inp[(size_t)(r0 + ty + 8 * j) * C + c0 + tx];
  __syncthreads();
#pragma unroll
  for (int j = 0; j < 4; j++)
    outp[(size_t)(c0 + ty + 8 * j) * R + r0 + tx] = f2bf(tile[tx][ty + 8 * j]);
}

// ---- router: fp32 logits, top-2, softmax over the pair. NO atomics. ----
__global__ void router_k(const float* __restrict__ x, const float* __restrict__ gw,
                         const float* __restrict__ gb, int* __restrict__ ti,
                         float* __restrict__ tw) {
  int wid = threadIdx.x >> 6, lane = threadIdx.x & 63;
  int t = blockIdx.x * 4 + wid;
  const float* xr = x + (size_t)t * D_;
  float acc[E_];
#pragma unroll
  for (int e = 0; e < E_; e++) acc[e] = 0.f;
#pragma unroll
  for (int it = 0; it < D_ / 64; it++) {
    int d = it * 64 + lane;
    float xv = xr[d];
    const float* g = gw + d * E_;
#pragma unroll
    for (int e = 0; e < E_; e++) acc[e] += xv * g[e];
  }
#pragma unroll
  for (int off = 32; off > 0; off >>= 1)
#pragma unroll
    for (int e = 0; e < E_; e++) acc[e] += __shfl_xor(acc[e], off);
  if (lane == 0) {
    float v[E_];
#pragma unroll
    for (int e = 0; e < E_; e++) v[e] = acc[e] + gb[e];
    int i0 = 0; float v0 = v[0];
#pragma unroll
    for (int e = 1; e < E_; e++) if (v[e] > v0) { v0 = v[e]; i0 = e; }
    int i1 = -1; float v1 = -3.4e38f;
#pragma unroll
    for (int e = 0; e < E_; e++) if (e != i0 && v[e] > v1) { v1 = v[e]; i1 = e; }
    float ex = expf(v1 - v0);           // <= 1, no overflow
    float w0 = 1.f / (1.f + ex);
    float w1 = ex / (1.f + ex);
    ti[2 * t] = i0; tw[2 * t] = w0;
    ti[2 * t + 1] = i1; tw[2 * t + 1] = w1;
  }
}

// ---- single-block histogram + 256-aligned exclusive prefix ----
__global__ void count_prefix_k(const int* __restrict__ ti, int* __restrict__ offs,
                               int* __restrict__ cursors) {
  __shared__ int scnt[4][E_];
  int tid = threadIdx.x;  // 256 threads
  int cnt[E_];
#pragma unroll
  for (int k = 0; k < E_; k++) cnt[k] = 0;
  for (int i = tid; i < NS; i += 256) {
    int e = ti[i];
#pragma unroll
    for (int k = 0; k < E_; k++) cnt[k] += (e == k) ? 1 : 0;
  }
#pragma unroll
  for (int off = 32; off > 0; off >>= 1)
#pragma unroll
    for (int k = 0; k < E_; k++) cnt[k] += __shfl_xor(cnt[k], off);
  int wid = tid >> 6, lane = tid & 63;
  if (lane == 0)
#pragma unroll
    for (int k = 0; k < E_; k++) scnt[wid][k] = cnt[k];
  __syncthreads();
  if (tid == 0) {
    int o = 0;
    for (int k = 0; k < E_; k++) {
      int c = scnt[0][k] + scnt[1][k] + scnt[2][k] + scnt[3][k];
      offs[k] = o;
      cursors[k] = o;
      o += (c + 255) & ~255;
    }
    offs[E_] = o;
  }
}

__global__ void fill_k(int* __restrict__ idx) {
  int s = blockIdx.x * 256 + threadIdx.x;
  if (s < CAP) idx[s] = 0;
}

// ---- wave-aggregated scatter: 8 atomics per wave; records slot of each assignment ----
__global__ void scatter_k(const int* __restrict__ ti, const float* __restrict__ tw,
                          int* __restrict__ cursors, int* __restrict__ idx,
                          int* __restrict__ pos_of) {
  int a = blockIdx.x * 256 + threadIdx.x;  // 0..NS-1
  int lane = threadIdx.x & 63;
  int e = ti[a];
  unsigned long long m[E_];
#pragma unroll
  for (int k = 0; k < E_; k++) m[k] = __ballot(e == k);
  int base = 0;
  if (lane < E_) base = atomicAdd(&cursors[lane], __popcll(m[lane]));
  int myBase = __shfl(base, e);
  unsigned long long m_mine = 0;
#pragma unroll
  for (int k = 0; k < E_; k++) if (e == k) m_mine = m[k];
  int rank = __popcll(m_mine & ((1ull << lane) - 1ull));
  int pos = myBase + rank;
  idx[pos] = a >> 1;
  pos_of[a] = pos;
}

// ---- gather routed token rows into bf16, slot-major ----
__global__ void gather_k(const float* __restrict__ x, const int* __restrict__ idx,
                         unsigned short* __restrict__ Xg) {
  int s = blockIdx.x;
  int t = idx[s];
  const float4* xr = (const float4*)(x + (size_t)t * D_);
  float4 v = xr[threadIdx.x];
  uint2 p;
  p.x = (unsigned)f2bf(v.x) | ((unsigned)f2bf(v.y) << 16);
  p.y = (unsigned)f2bf(v.z) | ((unsigned)f2bf(v.w) << 16);
  ((uint2*)(Xg + (size_t)s * D_))[threadIdx.x] = p;
}

// ---- grouped GEMM: 256x256 tile, BK=64, 8 waves (2Mx4N), double-buffered LDS,
// 8-phase counted-vmcnt schedule (T2+T3+T4+T5).
//
// LDS per tile buffer: 256 rows x 64 shorts, XOR chunk swizzle (physical chunk p
// of row r holds logical chunk p^(r&7)); reader for k-sub ks, quad q, row R uses
// chunk ((ks<<2)|q)^(R&7). Verified conflict-free (2-way = free).
//
// Phase plan per iteration (2 K-tiles; even tile -> buf0, odd -> buf1):
//   ph0 [vmcnt(2)+bar] compute E(mh0,ks0), issue A-odd q0,q2
//   ph1               compute E(mh0,ks1), issue B-odd q0,q1
//   ph2 [vmcnt(4)+bar] compute E(mh1,ks0), issue B-odd q2,q3
//   ph3               compute E(mh1,ks1), issue A-odd q1,q3
//   ph4 [vmcnt(2)+bar] compute O(mh0,ks0), issue A-next q0,q2
//   ph5               compute O(mh0,ks1), issue B-next q0,q1
//   ph6 [vmcnt(4)+bar] compute O(mh1,ks0), issue B-next q2,q3
//   ph7               compute O(mh1,ks1), issue A-next q1,q3
// Ledger (per-wave outstanding gld16): 8/6/8/6 at the four syncs; drains of 6/2/6/2
// cover exactly the groups each pair of phases reads. Never vmcnt(0) in the loop.
// Last iteration re-issues k=0 into the dead buffer to keep the ledger steady.
// sched_barrier(0x38F) = all-but-VMEM may cross: pins gld16 issue order.
template <int K, int N, bool GELU>
__global__ __launch_bounds__(512, 2) void gemm_k(const unsigned short* __restrict__ A,
                                                 const unsigned short* __restrict__ W,
                                                 const float* __restrict__ bias_all,
                                                 unsigned short* __restrict__ O,
                                                 const int* __restrict__ offs) {
  int slot0 = blockIdx.y * 256;
  if (slot0 >= offs[E_]) return;
  int e = 0;
  while (slot0 >= offs[e + 1]) e++;
  const unsigned short* Bp = W + (size_t)e * N * K;
  int n0 = blockIdx.x * 256;

  __shared__ unsigned short lA[2][256 * 64];
  __shared__ unsigned short lB[2][256 * 64];

  int tid = threadIdx.x;
  int wid = tid >> 6, lane = tid & 63;
  int wr = wid >> 2, wc = wid & 3;          // 2 x 4 wave grid
  int quad = lane >> 4, l15 = lane & 15;
  int l7 = l15 & 7;

  // staging lane mapping: wave covers 8 rows per issue, lane -> (row sr, chunk ch)
  int sr = lane >> 3;                       // 0..7
  int ch = (lane & 7) ^ sr;                 // pre-swizzled global chunk
  const unsigned short* gA = A + (size_t)(slot0 + 8 * wid + sr) * K + ch * 8;
  const unsigned short* gB = Bp + (size_t)(n0 + 8 * wid + sr) * K + ch * 8;

#define STAGE_A(buf, q, kk) gld16(gA + (size_t)(q) * 64 * K + (size_t)(kk), \
                                  &lA[buf][((q) * 64 + 8 * wid) * 64])
#define STAGE_B(buf, q, kk) gld16(gB + (size_t)(q) * 64 * K + (size_t)(kk), \
                                  &lB[buf][((q) * 64 + 8 * wid) * 64])
#define SYNCV(n) asm volatile("s_waitcnt vmcnt(" #n ")\n\ts_barrier" ::: "memory")

#define PH(buf, mh, ks, ...) do {                                                   \
    short8 af_[4], bf_[4];                                                          \
    _Pragma("unroll")                                                               \
    for (int m_ = 0; m_ < 4; m_++) {                                                \
      int row_ = 128 * wr + 64 * (mh) + 16 * m_ + l15;                              \
      af_[m_] = *(const short8*)&lA[buf][row_ * 64 + ((((ks) << 2) | quad) ^ l7) * 8]; \
    }                                                                               \
    _Pragma("unroll")                                                               \
    for (int n_ = 0; n_ < 4; n_++) {                                                \
      int row_ = 64 * wc + 16 * n_ + l15;                                           \
      bf_[n_] = *(const short8*)&lB[buf][row_ * 64 + ((((ks) << 2) | quad) ^ l7) * 8]; \
    }                                                                               \
    __VA_ARGS__                                                                     \
    __builtin_amdgcn_sched_barrier(0x38F);                                          \
    __builtin_amdgcn_s_setprio(1);                                                  \
    _Pragma("unroll")                                                               \
    for (int m_ = 0; m_ < 4; m_++) {                                                \
      _Pragma("unroll")                                                             \
      for (int n_ = 0; n_ < 4; n_++)                                                \
        acc[4 * (mh) + m_][n_] = __builtin_amdgcn_mfma_f32_16x16x32_bf16(           \
            af_[m_], bf_[n_], acc[4 * (mh) + m_][n_], 0, 0, 0);                     \
    }                                                                               \
    __builtin_amdgcn_s_setprio(0);                                                  \
  } while (0)

  floatx4 acc[8][4];
#pragma unroll
  for (int mi = 0; mi < 8; mi++)
#pragma unroll
    for (int ni = 0; ni < 4; ni++) acc[mi][ni] = (floatx4){0.f, 0.f, 0.f, 0.f};

  // prologue: stage tile 0 into buf0 in steady-state issue order (A02, B, A13)
  STAGE_A(0, 0, 0); STAGE_A(0, 2, 0);
  STAGE_B(0, 0, 0); STAGE_B(0, 1, 0);
  STAGE_B(0, 2, 0); STAGE_B(0, 3, 0);
  __builtin_amdgcn_sched_barrier(0x38F);
  STAGE_A(0, 1, 0); STAGE_A(0, 3, 0);

  constexpr int NI = K / 128;  // two K-tiles per iteration
  for (int i = 0; i < NI; i++) {
    int kO = (2 * i + 1) * 64;
    int kE = (i + 1 < NI) ? (2 * i + 2) * 64 : 0;  // dummy re-stage on last iter
    SYNCV(2);
    PH(0, 0, 0, STAGE_A(1, 0, kO); STAGE_A(1, 2, kO););
    PH(0, 0, 1, STAGE_B(1, 0, kO); STAGE_B(1, 1, kO););
    SYNCV(4);
    PH(0, 1, 0, STAGE_B(1, 2, kO); STAGE_B(1, 3, kO););
    PH(0, 1, 1, STAGE_A(1, 1, kO); STAGE_A(1, 3, kO););
    SYNCV(2);
    PH(1, 0, 0, STAGE_A(0, 0, kE); STAGE_A(0, 2, kE););
    PH(1, 0, 1, STAGE_B(0, 0, kE); STAGE_B(0, 1, kE););
    SYNCV(4);
    PH(1, 1, 0, STAGE_B(0, 2, kE); STAGE_B(0, 3, kE););
    PH(1, 1, 1, STAGE_A(0, 1, kE); STAGE_A(0, 3, kE););
  }

  const float* bias = bias_all + (size_t)e * N;
#pragma unroll
  for (int mi = 0; mi < 8; mi++) {
    int row = slot0 + 128 * wr + 16 * mi + quad * 4;
#pragma unroll
    for (int ni = 0; ni < 4; ni++) {
      int col = n0 + 64 * wc + 16 * ni + l15;
      float bv = bias[col];
#pragma unroll
      for (int r = 0; r < 4; r++) {
        float v = acc[mi][ni][r] + bv;
        if (GELU) v = gelu_f(v);
        O[(size_t)(row + r) * N + col] = f2bf(v);
      }
    }
  }
#undef STAGE_A
#undef STAGE_B
#undef SYNCV
#undef PH
}

// ---- combine: out[t] = w0*Yg[pos(2t)] + w1*Yg[pos(2t+1)] ----
__global__ void combine_k(const unsigned short* __restrict__ Yg,
                          const int* __restrict__ pos_of,
                          const float* __restrict__ tw, float* __restrict__ out) {
  int t = blockIdx.x;
  int p0 = pos_of[2 * t], p1 = pos_of[2 * t + 1];
  float w0 = tw[2 * t], w1 = tw[2 * t + 1];
  uint2 a = ((const uint2*)(Yg + (size_t)p0 * D_))[threadIdx.x];
  uint2 b = ((const uint2*)(Yg + (size_t)p1 * D_))[threadIdx.x];
  float4 r;
  r.x = w0 * bf2f(a.x & 0xffffu) + w1 * bf2f(b.x & 0xffffu);
  r.y = w0 * bf2f(a.x >> 16)     + w1 * bf2f(b.x >> 16);
  r.z = w0 * bf2f(a.y & 0xffffu) + w1 * bf2f(b.y & 0xffffu);
  r.w = w0 * bf2f(a.y >> 16)     + w1 * bf2f(b.y >> 16);
  ((float4*)(out + (size_t)t * D_))[threadIdx.x] = r;
}

extern "C" void kernel_launch(void* const* d_in, const int* in_sizes, int n_in,
                              void* d_out, int out_size, void* d_ws, size_t ws_size,
                              hipStream_t stream) {
  const float* x  = (const float*)d_in[0];
  const float* gw = (const float*)d_in[1];
  const float* gb = (const float*)d_in[2];
  const float* w1 = (const float*)d_in[3];
  const float* b1 = (const float*)d_in[4];
  const float* w2 = (const float*)d_in[5];
  const float* b2 = (const float*)d_in[6];
  float* out = (float*)d_out;

  char* p = (char*)d_ws;
  unsigned short* w1t = (unsigned short*)p; p += (size_t)E_ * D_ * F_ * 2;
  unsigned short* w2t = (unsigned short*)p; p += (size_t)E_ * D_ * F_ * 2;
  unsigned short* Xg  = (unsigned short*)p; p += (size_t)CAP * D_ * 2;
  unsigned short* H   = (unsigned short*)p; p += (size_t)CAP * F_ * 2;
  int*   idx    = (int*)p; p += (size_t)CAP * 4;
  int*   pos_of = (int*)p; p += (size_t)NS * 4;
  int*   ti     = (int*)p; p += (size_t)NS * 4;
  float* tw     = (float*)p; p += (size_t)NS * 4;
  int* cursors = (int*)p; p += 64;
  int* offs    = (int*)p; p += 64;
  unsigned short* Yg = Xg;  // alias: Xg dead after gemm1, Yg born in gemm2

  dim3 tb(32, 8);
  transpose_cvt<<<dim3(F_ / 32, D_ / 32, E_), tb, 0, stream>>>(w1, w1t, D_, F_);
  transpose_cvt<<<dim3(D_ / 32, F_ / 32, E_), tb, 0, stream>>>(w2, w2t, F_, D_);
  router_k<<<NT / 4, 256, 0, stream>>>(x, gw, gb, ti, tw);
  count_prefix_k<<<1, 256, 0, stream>>>(ti, offs, cursors);
  fill_k<<<(CAP + 255) / 256, 256, 0, stream>>>(idx);
  scatter_k<<<NS / 256, 256, 0, stream>>>(ti, tw, cursors, idx, pos_of);
  gather_k<<<CAP, 256, 0, stream>>>(x, idx, Xg);
  gemm_k<D_, F_, true><<<dim3(F_ / 256, CAP / 256), 512, 0, stream>>>(Xg, w1t, b1, H, offs);
  gemm_k<F_, D_, false><<<dim3(D_ / 256, CAP / 256), 512, 0, stream>>>(H, w2t, b2, Yg, offs);
  combine_k<<<NT, 256, 0, stream>>>(Yg, pos_of, tw, out);
}

// Round 3
// 496.669 us; speedup vs baseline: 1.0257x; 1.0257x over previous
//
#include <hip/hip_runtime.h>
#include <hip/hip_bf16.h>
#include <math.h>

#define B_ 4
#define T_ 2048
#define D_ 1024
#define F_ 2048
#define E_ 8
#define NT (B_ * T_)          // 8192 tokens
#define NS (NT * 2)           // 16384 routed assignments (K=2)
#define CAP (NS + E_ * 256)   // 18432 slots: 256-aligned per-expert segments always fit

typedef __attribute__((ext_vector_type(8))) short short8;
typedef __attribute__((ext_vector_type(4))) float floatx4;

static __device__ __forceinline__ unsigned short f2bf(float f) {
  union { float f; unsigned u; } a; a.f = f;
  unsigned r = a.u + 0x7fffu + ((a.u >> 16) & 1u);  // RNE
  return (unsigned short)(r >> 16);
}

static __device__ __forceinline__ float bf2f(unsigned u) {
  union { unsigned u; float f; } a; a.u = u << 16; return a.f;
}

static __device__ __forceinline__ void gld16(const unsigned short* g, unsigned short* l) {
  __builtin_amdgcn_global_load_lds(
      (const __attribute__((address_space(1))) void*)g,
      (__attribute__((address_space(3))) void*)l, 16, 0, 0);
}

// Branchless GELU: Abramowitz-Stegun 7.1.26 erf (|err| < 1.5e-7), hw exp2/rcp.
static __device__ __forceinline__ float gelu_f(float v) {
  float ax = fabsf(v) * 0.70710678118654752f;
  float t = __builtin_amdgcn_rcpf(1.f + 0.3275911f * ax);
  float e = __builtin_amdgcn_exp2f(-ax * ax * 1.44269504088896f);  // exp(-ax^2)
  float p = t * (0.254829592f +
            t * (-0.284496736f +
            t * (1.421413741f +
            t * (-1.453152027f +
            t * 1.061405429f))));
  float er = 1.f - p * e;
  er = copysignf(er, v);
  return 0.5f * v * (1.f + er);
}

// ---- weight transpose + fp32->bf16 convert: in [E][R][C] -> out [E][C][R] ----
__global__ void transpose_cvt(const float* __restrict__ in, unsigned short* __restrict__ out,
                              int R, int C) {
  __shared__ float tile[32][33];
  int e = blockIdx.z;
  const float* inp = in + (size_t)e * R * C;
  unsigned short* outp = out + (size_t)e * R * C;
  int c0 = blockIdx.x * 32, r0 = blockIdx.y * 32;
  int tx = threadIdx.x, ty = threadIdx.y;
#pragma unroll
  for (int j = 0; j < 4; j++)
    tile[ty + 8 * j][tx] = inp[(size_t)(r0 + ty + 8 * j) * C + c0 + tx];
  __syncthreads();
#pragma unroll
  for (int j = 0; j < 4; j++)
    outp[(size_t)(c0 + ty + 8 * j) * R + r0 + tx] = f2bf(tile[tx][ty + 8 * j]);
}

// ---- router: fp32 logits, top-2, softmax over the pair. NO atomics. ----
__global__ void router_k(const float* __restrict__ x, const float* __restrict__ gw,
                         const float* __restrict__ gb, int* __restrict__ ti,
                         float* __restrict__ tw) {
  int wid = threadIdx.x >> 6, lane = threadIdx.x & 63;
  int t = blockIdx.x * 4 + wid;
  const float* xr = x + (size_t)t * D_;
  float acc[E_];
#pragma unroll
  for (int e = 0; e < E_; e++) acc[e] = 0.f;
#pragma unroll
  for (int it = 0; it < D_ / 64; it++) {
    int d = it * 64 + lane;
    float xv = xr[d];
    const float* g = gw + d * E_;
#pragma unroll
    for (int e = 0; e < E_; e++) acc[e] += xv * g[e];
  }
#pragma unroll
  for (int off = 32; off > 0; off >>= 1)
#pragma unroll
    for (int e = 0; e < E_; e++) acc[e] += __shfl_xor(acc[e], off);
  if (lane == 0) {
    float v[E_];
#pragma unroll
    for (int e = 0; e < E_; e++) v[e] = acc[e] + gb[e];
    int i0 = 0; float v0 = v[0];
#pragma unroll
    for (int e = 1; e < E_; e++) if (v[e] > v0) { v0 = v[e]; i0 = e; }
    int i1 = -1; float v1 = -3.4e38f;
#pragma unroll
    for (int e = 0; e < E_; e++) if (e != i0 && v[e] > v1) { v1 = v[e]; i1 = e; }
    float ex = expf(v1 - v0);           // <= 1, no overflow
    float w0 = 1.f / (1.f + ex);
    float w1 = ex / (1.f + ex);
    ti[2 * t] = i0; tw[2 * t] = w0;
    ti[2 * t + 1] = i1; tw[2 * t + 1] = w1;
  }
}

// ---- single-block histogram + 256-aligned exclusive prefix ----
__global__ void count_prefix_k(const int* __restrict__ ti, int* __restrict__ offs,
                               int* __restrict__ cursors) {
  __shared__ int scnt[4][E_];
  int tid = threadIdx.x;  // 256 threads
  int cnt[E_];
#pragma unroll
  for (int k = 0; k < E_; k++) cnt[k] = 0;
  for (int i = tid; i < NS; i += 256) {
    int e = ti[i];
#pragma unroll
    for (int k = 0; k < E_; k++) cnt[k] += (e == k) ? 1 : 0;
  }
#pragma unroll
  for (int off = 32; off > 0; off >>= 1)
#pragma unroll
    for (int k = 0; k < E_; k++) cnt[k] += __shfl_xor(cnt[k], off);
  int wid = tid >> 6, lane = tid & 63;
  if (lane == 0)
#pragma unroll
    for (int k = 0; k < E_; k++) scnt[wid][k] = cnt[k];
  __syncthreads();
  if (tid == 0) {
    int o = 0;
    for (int k = 0; k < E_; k++) {
      int c = scnt[0][k] + scnt[1][k] + scnt[2][k] + scnt[3][k];
      offs[k] = o;
      cursors[k] = o;
      o += (c + 255) & ~255;
    }
    offs[E_] = o;
  }
}

__global__ void fill_k(int* __restrict__ idx) {
  int s = blockIdx.x * 256 + threadIdx.x;
  if (s < CAP) idx[s] = 0;
}

// ---- wave-aggregated scatter: 8 atomics per wave; records slot of each assignment ----
__global__ void scatter_k(const int* __restrict__ ti, const float* __restrict__ tw,
                          int* __restrict__ cursors, int* __restrict__ idx,
                          int* __restrict__ pos_of) {
  int a = blockIdx.x * 256 + threadIdx.x;  // 0..NS-1
  int lane = threadIdx.x & 63;
  int e = ti[a];
  unsigned long long m[E_];
#pragma unroll
  for (int k = 0; k < E_; k++) m[k] = __ballot(e == k);
  int base = 0;
  if (lane < E_) base = atomicAdd(&cursors[lane], __popcll(m[lane]));
  int myBase = __shfl(base, e);
  unsigned long long m_mine = 0;
#pragma unroll
  for (int k = 0; k < E_; k++) if (e == k) m_mine = m[k];
  int rank = __popcll(m_mine & ((1ull << lane) - 1ull));
  int pos = myBase + rank;
  idx[pos] = a >> 1;
  pos_of[a] = pos;
}

// ---- gather routed token rows into bf16, slot-major ----
__global__ void gather_k(const float* __restrict__ x, const int* __restrict__ idx,
                         unsigned short* __restrict__ Xg) {
  int s = blockIdx.x;
  int t = idx[s];
  const float4* xr = (const float4*)(x + (size_t)t * D_);
  float4 v = xr[threadIdx.x];
  uint2 p;
  p.x = (unsigned)f2bf(v.x) | ((unsigned)f2bf(v.y) << 16);
  p.y = (unsigned)f2bf(v.z) | ((unsigned)f2bf(v.w) << 16);
  ((uint2*)(Xg + (size_t)s * D_))[threadIdx.x] = p;
}

// ---- grouped GEMM: 256x256 tile, BK=32, 8 waves (2Mx4N), 4-deep LDS buffer
// rotation, per-16-MFMA barrier-pair lockstep, counted vmcnt (never 0).
//
// Stagger: K-tile t's buffers (buf t&3) are staged during K-tile t-2 -> ~2 K-tiles
// (>2000 cyc) of issue->wait slack. Ledger per wave: entering tile t, outstanding
// = {A(t+1),B(t+1)} = 4 loads; phase 0 issues A(t+2) (2), phase 1 issues B(t+2)
// (2) -> 8; vmcnt(4) before the closing barrier retires exactly t+1's loads.
// vmcnt precedes s_barrier, so barrier-release implies every wave's stage loads
// for tile t+1 have committed to LDS (cross-wave visibility).
//
// LDS swizzle (BK=32, 64-B rows): phys 16-B chunk of logical (row r, k-chunk q)
// = (((r&1)<<2)|q) ^ ((r>>1)&7), applied within each 128-B superrow. Every
// 16-lane group of a ds_read_b128 then hits each bank exactly 2x (free).
// Staging keeps the LDS dest linear (gld16 requirement) and pre-permutes the
// per-lane GLOBAL source: lane i covers logical (r_l, q_l) with
// c = (i&7)^(i>>3), r_l = (i>>3)*2 + (c>>2), q_l = c&3.
template <int K, int N, bool GELU>
__global__ __launch_bounds__(512, 2) void gemm_k(const unsigned short* __restrict__ A,
                                                 const unsigned short* __restrict__ W,
                                                 const float* __restrict__ bias_all,
                                                 unsigned short* __restrict__ O,
                                                 const int* __restrict__ offs) {
  int slot0 = blockIdx.x * 256;   // x = row-tiles; gridDim.x % 8 == 0 -> all
  if (slot0 >= offs[E_]) return;  // col-tiles of a row-block share an XCD (L2 A-reuse)
  int e = 0;
  while (slot0 >= offs[e + 1]) e++;
  const unsigned short* Bp = W + (size_t)e * N * K;
  int n0 = blockIdx.y * 256;

  __shared__ unsigned short lA[4][256 * 32];
  __shared__ unsigned short lB[4][256 * 32];

  int tid = threadIdx.x;
  int wid = tid >> 6, lane = tid & 63;
  int wr = wid >> 2, wc = wid & 3;          // 2M x 4N wave grid, per-wave out 128x64
  int quad = lane >> 4, l15 = lane & 15;

  // LDS read bases (shorts). Row r = 16-aligned base + l15, so (r>>1)&7 = (l15>>1)&7.
  int cph = (((l15 & 1) << 2) | quad) ^ ((l15 >> 1) & 7);
  int ra = ((wr << 6) + (l15 >> 1)) * 64 + cph * 8;   // + m*512 for m-th 16-row tile
  int rb = ((wc << 5) + (l15 >> 1)) * 64 + cph * 8;   // + n*512

  // staging lane map (see header comment)
  int srl = lane >> 3;
  int clog = (lane & 7) ^ srl;
  int r_l = (srl << 1) | (clog >> 2);
  int q_l = clog & 3;
  const unsigned short* gA = A + (size_t)(slot0 + 16 * wid + r_l) * K + q_l * 8;
  const unsigned short* gB = Bp + (size_t)(n0 + 16 * wid + r_l) * K + q_l * 8;

#define STG(gp, larr, buf, kt) do {                                             \
    gld16(gp + (size_t)(kt) * 32, &larr[buf][(16 * wid) * 32]);                 \
    gld16(gp + (size_t)128 * K + (size_t)(kt) * 32,                             \
          &larr[buf][(16 * wid + 128) * 32]);                                   \
  } while (0)

  floatx4 acc[8][4];
#pragma unroll
  for (int mi = 0; mi < 8; mi++)
#pragma unroll
    for (int ni = 0; ni < 4; ni++) acc[mi][ni] = (floatx4){0.f, 0.f, 0.f, 0.f};

  // prologue: stage K-tiles 0 and 1; drain tile 0 (vmcnt(4) leaves tile 1 in flight)
  STG(gA, lA, 0, 0); STG(gB, lB, 0, 0);
  STG(gA, lA, 1, 1); STG(gB, lB, 1, 1);
  asm volatile("s_waitcnt vmcnt(4)\ns_barrier" ::: "memory");

  constexpr int NK = K / 32;
  for (int t = 0; t < NK; t++) {
    int buf = t & 3, sb = (t + 2) & 3;
    int kt = (t + 2 < NK) ? (t + 2) : 0;  // dummy re-stage keeps the ledger uniform
    // ---- phase 0: A rows 128wr..+63 (m 0..3) + all 4 B frags; stage A(t+2)
    short8 af[4], bfr[4];
#pragma unroll
    for (int m = 0; m < 4; m++) af[m] = *(const short8*)&lA[buf][ra + m * 512];
#pragma unroll
    for (int n = 0; n < 4; n++) bfr[n] = *(const short8*)&lB[buf][rb + n * 512];
    STG(gA, lA, sb, kt);
    asm volatile("s_barrier" ::: "memory");
    __builtin_amdgcn_s_setprio(1);
#pragma unroll
    for (int m = 0; m < 4; m++)
#pragma unroll
      for (int n = 0; n < 4; n++)
        acc[m][n] = __builtin_amdgcn_mfma_f32_16x16x32_bf16(af[m], bfr[n], acc[m][n], 0, 0, 0);
    __builtin_amdgcn_s_setprio(0);
    asm volatile("s_barrier" ::: "memory");
    // ---- phase 1: A rows 128wr+64..+127 (m 4..7), reuse bfr; stage B(t+2)
    short8 ag[4];
#pragma unroll
    for (int m = 0; m < 4; m++) ag[m] = *(const short8*)&lA[buf][ra + (m + 4) * 512];
    STG(gB, lB, sb, kt);
    asm volatile("s_barrier" ::: "memory");
    __builtin_amdgcn_s_setprio(1);
#pragma unroll
    for (int m = 0; m < 4; m++)
#pragma unroll
      for (int n = 0; n < 4; n++)
        acc[m + 4][n] = __builtin_amdgcn_mfma_f32_16x16x32_bf16(ag[m], bfr[n], acc[m + 4][n], 0, 0, 0);
    __builtin_amdgcn_s_setprio(0);
    asm volatile("s_waitcnt vmcnt(4)\ns_barrier" ::: "memory");
  }
#undef STG

  const float* bias = bias_all + (size_t)e * N;
#pragma unroll
  for (int mi = 0; mi < 8; mi++) {
    int row = slot0 + 128 * wr + 16 * mi + quad * 4;
#pragma unroll
    for (int ni = 0; ni < 4; ni++) {
      int col = n0 + 64 * wc + 16 * ni + l15;
      float bv = bias[col];
#pragma unroll
      for (int r = 0; r < 4; r++) {
        float v = acc[mi][ni][r] + bv;
        if (GELU) v = gelu_f(v);
        O[(size_t)(row + r) * N + col] = f2bf(v);
      }
    }
  }
}

// ---- combine: out[t] = w0*Yg[pos(2t)] + w1*Yg[pos(2t+1)] ----
__global__ void combine_k(const unsigned short* __restrict__ Yg,
                          const int* __restrict__ pos_of,
                          const float* __restrict__ tw, float* __restrict__ out) {
  int t = blockIdx.x;
  int p0 = pos_of[2 * t], p1 = pos_of[2 * t + 1];
  float w0 = tw[2 * t], w1 = tw[2 * t + 1];
  uint2 a = ((const uint2*)(Yg + (size_t)p0 * D_))[threadIdx.x];
  uint2 b = ((const uint2*)(Yg + (size_t)p1 * D_))[threadIdx.x];
  float4 r;
  r.x = w0 * bf2f(a.x & 0xffffu) + w1 * bf2f(b.x & 0xffffu);
  r.y = w0 * bf2f(a.x >> 16)     + w1 * bf2f(b.x >> 16);
  r.z = w0 * bf2f(a.y & 0xffffu) + w1 * bf2f(b.y & 0xffffu);
  r.w = w0 * bf2f(a.y >> 16)     + w1 * bf2f(b.y >> 16);
  ((float4*)(out + (size_t)t * D_))[threadIdx.x] = r;
}

extern "C" void kernel_launch(void* const* d_in, const int* in_sizes, int n_in,
                              void* d_out, int out_size, void* d_ws, size_t ws_size,
                              hipStream_t stream) {
  const float* x  = (const float*)d_in[0];
  const float* gw = (const float*)d_in[1];
  const float* gb = (const float*)d_in[2];
  const float* w1 = (const float*)d_in[3];
  const float* b1 = (const float*)d_in[4];
  const float* w2 = (const float*)d_in[5];
  const float* b2 = (const float*)d_in[6];
  float* out = (float*)d_out;

  char* p = (char*)d_ws;
  unsigned short* w1t = (unsigned short*)p; p += (size_t)E_ * D_ * F_ * 2;
  unsigned short* w2t = (unsigned short*)p; p += (size_t)E_ * D_ * F_ * 2;
  unsigned short* Xg  = (unsigned short*)p; p += (size_t)CAP * D_ * 2;
  unsigned short* H   = (unsigned short*)p; p += (size_t)CAP * F_ * 2;
  int*   idx    = (int*)p; p += (size_t)CAP * 4;
  int*   pos_of = (int*)p; p += (size_t)NS * 4;
  int*   ti     = (int*)p; p += (size_t)NS * 4;
  float* tw     = (float*)p; p += (size_t)NS * 4;
  int* cursors = (int*)p; p += 64;
  int* offs    = (int*)p; p += 64;
  unsigned short* Yg = Xg;  // alias: Xg dead after gemm1, Yg born in gemm2

  dim3 tb(32, 8);
  transpose_cvt<<<dim3(F_ / 32, D_ / 32, E_), tb, 0, stream>>>(w1, w1t, D_, F_);
  transpose_cvt<<<dim3(D_ / 32, F_ / 32, E_), tb, 0, stream>>>(w2, w2t, F_, D_);
  router_k<<<NT / 4, 256, 0, stream>>>(x, gw, gb, ti, tw);
  count_prefix_k<<<1, 256, 0, stream>>>(ti, offs, cursors);
  fill_k<<<(CAP + 255) / 256, 256, 0, stream>>>(idx);
  scatter_k<<<NS / 256, 256, 0, stream>>>(ti, tw, cursors, idx, pos_of);
  gather_k<<<CAP, 256, 0, stream>>>(x, idx, Xg);
  gemm_k<D_, F_, true><<<dim3(CAP / 256, F_ / 256), 512, 0, stream>>>(Xg, w1t, b1, H, offs);
  gemm_k<F_, D_, false><<<dim3(CAP / 256, D_ / 256), 512, 0, stream>>>(H, w2t, b2, Yg, offs);
  combine_k<<<NT, 256, 0, stream>>>(Yg, pos_of, tw, out);
}

// Round 4
// 484.159 us; speedup vs baseline: 1.0522x; 1.0258x over previous
//
#include <hip/hip_runtime.h>
#include <hip/hip_bf16.h>
#include <math.h>

#define B_ 4
#define T_ 2048
#define D_ 1024
#define F_ 2048
#define E_ 8
#define NT (B_ * T_)          // 8192 tokens
#define NS (NT * 2)           // 16384 routed assignments (K=2)
#define CAP (NS + E_ * 128)   // 17408 slots: 128-aligned per-expert segments always fit

typedef __attribute__((ext_vector_type(8))) short short8;
typedef __attribute__((ext_vector_type(4))) float floatx4;

static __device__ __forceinline__ unsigned short f2bf(float f) {
  union { float f; unsigned u; } a; a.f = f;
  unsigned r = a.u + 0x7fffu + ((a.u >> 16) & 1u);  // RNE
  return (unsigned short)(r >> 16);
}

static __device__ __forceinline__ float bf2f(unsigned u) {
  union { unsigned u; float f; } a; a.u = u << 16; return a.f;
}

static __device__ __forceinline__ void gld16(const unsigned short* g, unsigned short* l) {
  __builtin_amdgcn_global_load_lds(
      (const __attribute__((address_space(1))) void*)g,
      (__attribute__((address_space(3))) void*)l, 16, 0, 0);
}

// Branchless GELU: Abramowitz-Stegun 7.1.26 erf (|err| < 1.5e-7), hw exp2/rcp.
static __device__ __forceinline__ float gelu_f(float v) {
  float ax = fabsf(v) * 0.70710678118654752f;
  float t = __builtin_amdgcn_rcpf(1.f + 0.3275911f * ax);
  float e = __builtin_amdgcn_exp2f(-ax * ax * 1.44269504088896f);  // exp(-ax^2)
  float p = t * (0.254829592f +
            t * (-0.284496736f +
            t * (1.421413741f +
            t * (-1.453152027f +
            t * 1.061405429f))));
  float er = 1.f - p * e;
  er = copysignf(er, v);
  return 0.5f * v * (1.f + er);
}

// ---- weight transpose + fp32->bf16 convert: in [E][R][C] -> out [E][C][R] ----
__global__ void transpose_cvt(const float* __restrict__ in, unsigned short* __restrict__ out,
                              int R, int C) {
  __shared__ float tile[32][33];
  int e = blockIdx.z;
  const float* inp = in + (size_t)e * R * C;
  unsigned short* outp = out + (size_t)e * R * C;
  int c0 = blockIdx.x * 32, r0 = blockIdx.y * 32;
  int tx = threadIdx.x, ty = threadIdx.y;
#pragma unroll
  for (int j = 0; j < 4; j++)
    tile[ty + 8 * j][tx] = inp[(size_t)(r0 + ty + 8 * j) * C + c0 + tx];
  __syncthreads();
#pragma unroll
  for (int j = 0; j < 4; j++)
    outp[(size_t)(c0 + ty + 8 * j) * R + r0 + tx] = f2bf(tile[tx][ty + 8 * j]);
}

// ---- router: fp32 logits, top-2, softmax over the pair. NO atomics. ----
__global__ void router_k(const float* __restrict__ x, const float* __restrict__ gw,
                         const float* __restrict__ gb, int* __restrict__ ti,
                         float* __restrict__ tw) {
  int wid = threadIdx.x >> 6, lane = threadIdx.x & 63;
  int t = blockIdx.x * 4 + wid;
  const float* xr = x + (size_t)t * D_;
  float acc[E_];
#pragma unroll
  for (int e = 0; e < E_; e++) acc[e] = 0.f;
#pragma unroll
  for (int it = 0; it < D_ / 64; it++) {
    int d = it * 64 + lane;
    float xv = xr[d];
    const float* g = gw + d * E_;
#pragma unroll
    for (int e = 0; e < E_; e++) acc[e] += xv * g[e];
  }
#pragma unroll
  for (int off = 32; off > 0; off >>= 1)
#pragma unroll
    for (int e = 0; e < E_; e++) acc[e] += __shfl_xor(acc[e], off);
  if (lane == 0) {
    float v[E_];
#pragma unroll
    for (int e = 0; e < E_; e++) v[e] = acc[e] + gb[e];
    int i0 = 0; float v0 = v[0];
#pragma unroll
    for (int e = 1; e < E_; e++) if (v[e] > v0) { v0 = v[e]; i0 = e; }
    int i1 = -1; float v1 = -3.4e38f;
#pragma unroll
    for (int e = 0; e < E_; e++) if (e != i0 && v[e] > v1) { v1 = v[e]; i1 = e; }
    float ex = expf(v1 - v0);           // <= 1, no overflow
    float w0 = 1.f / (1.f + ex);
    float w1 = ex / (1.f + ex);
    ti[2 * t] = i0; tw[2 * t] = w0;
    ti[2 * t + 1] = i1; tw[2 * t + 1] = w1;
  }
}

// ---- single-block histogram + 128-aligned exclusive prefix ----
__global__ void count_prefix_k(const int* __restrict__ ti, int* __restrict__ offs,
                               int* __restrict__ cursors) {
  __shared__ int scnt[4][E_];
  int tid = threadIdx.x;  // 256 threads
  int cnt[E_];
#pragma unroll
  for (int k = 0; k < E_; k++) cnt[k] = 0;
  for (int i = tid; i < NS; i += 256) {
    int e = ti[i];
#pragma unroll
    for (int k = 0; k < E_; k++) cnt[k] += (e == k) ? 1 : 0;
  }
#pragma unroll
  for (int off = 32; off > 0; off >>= 1)
#pragma unroll
    for (int k = 0; k < E_; k++) cnt[k] += __shfl_xor(cnt[k], off);
  int wid = tid >> 6, lane = tid & 63;
  if (lane == 0)
#pragma unroll
    for (int k = 0; k < E_; k++) scnt[wid][k] = cnt[k];
  __syncthreads();
  if (tid == 0) {
    int o = 0;
    for (int k = 0; k < E_; k++) {
      int c = scnt[0][k] + scnt[1][k] + scnt[2][k] + scnt[3][k];
      offs[k] = o;
      cursors[k] = o;
      o += (c + 127) & ~127;
    }
    offs[E_] = o;
  }
}

// ---- wave-aggregated scatter: 8 atomics per wave; records slot of each assignment ----
__global__ void scatter_k(const int* __restrict__ ti, const float* __restrict__ tw,
                          int* __restrict__ cursors, int* __restrict__ idx,
                          int* __restrict__ pos_of) {
  int a = blockIdx.x * 256 + threadIdx.x;  // 0..NS-1
  int lane = threadIdx.x & 63;
  int e = ti[a];
  unsigned long long m[E_];
#pragma unroll
  for (int k = 0; k < E_; k++) m[k] = __ballot(e == k);
  int base = 0;
  if (lane < E_) base = atomicAdd(&cursors[lane], __popcll(m[lane]));
  int myBase = __shfl(base, e);
  unsigned long long m_mine = 0;
#pragma unroll
  for (int k = 0; k < E_; k++) if (e == k) m_mine = m[k];
  int rank = __popcll(m_mine & ((1ull << lane) - 1ull));
  int pos = myBase + rank;
  idx[pos] = a >> 1;
  pos_of[a] = pos;
}

// ---- gather routed token rows into bf16, slot-major. Pad slots hold stale
// workspace garbage (fill pass removed): clamp into [0,NT) — their outputs are
// never combined, so any in-bounds row is fine. ----
__global__ void gather_k(const float* __restrict__ x, const int* __restrict__ idx,
                         unsigned short* __restrict__ Xg) {
  int s = blockIdx.x;
  int t = idx[s];
  t = ((unsigned)t < (unsigned)NT) ? t : 0;
  const float4* xr = (const float4*)(x + (size_t)t * D_);
  float4 v = xr[threadIdx.x];
  uint2 p;
  p.x = (unsigned)f2bf(v.x) | ((unsigned)f2bf(v.y) << 16);
  p.y = (unsigned)f2bf(v.z) | ((unsigned)f2bf(v.w) << 16);
  ((uint2*)(Xg + (size_t)s * D_))[threadIdx.x] = p;
}

// ---- grouped GEMM: 128x128 tile, BK=32, 4 waves (2Mx2N), 3-buffer LDS
// rotation, counted vmcnt (never 0), one barrier per K-step.
//
// Regime: 48 KB LDS -> 3 blocks/CU (12 waves/CU) — multi-block coverage (m114)
// PLUS in-schedule latency hiding. Stagger: K-step t's buffers staged at top of
// step t-2 (~2 K-steps ≈ 500 cyc of slack). Ledger per wave: entering step t,
// outstanding = step t+1's 4 gld16; step t issues 4 for t+2 -> 8; vmcnt(4)
// before the barrier retires exactly t+1's group. vmcnt precedes s_barrier ->
// barrier-release implies every wave's stage for t+1 is committed to LDS.
// Tail dummy-stages kt=0 to keep the ledger uniform. Buffer indices are
// compile-time (loop unrolled in groups of 3).
//
// LDS swizzle (BK=32, 64-B rows, verified 0 conflicts in R1/R3): phys 16-B
// chunk of logical (row r, k-chunk q) = (((r&1)<<2)|q) ^ ((r>>1)&7) within each
// 128-B superrow-pair group. Staging keeps LDS dest linear (gld16 requirement)
// and pre-permutes the per-lane GLOBAL source: lane i covers logical (r_l,q_l)
// with c = (i&7)^(i>>3), r_l = (i>>3)*2 + (c>>2), q_l = c&3.
template <int K, int N, bool GELU>
__global__ __launch_bounds__(256, 3) void gemm_k(const unsigned short* __restrict__ A,
                                                 const unsigned short* __restrict__ W,
                                                 const float* __restrict__ bias_all,
                                                 unsigned short* __restrict__ O,
                                                 const int* __restrict__ offs) {
  int slot0 = blockIdx.y * 128;
  if (slot0 >= offs[E_]) return;
  int e = 0;
  while (slot0 >= offs[e + 1]) e++;
  const unsigned short* Bp = W + (size_t)e * N * K;
  int n0 = blockIdx.x * 128;

  __shared__ unsigned short lA[3][128 * 32];
  __shared__ unsigned short lB[3][128 * 32];

  int tid = threadIdx.x;
  int wid = tid >> 6, lane = tid & 63;
  int wr = wid >> 1, wc = wid & 1;          // 2M x 2N wave grid, per-wave out 64x64
  int quad = lane >> 4, l15 = lane & 15;

  // LDS read bases (shorts): row r = 16-aligned base + l15 -> (r>>1)&7 = (l15>>1)&7
  int cph = (((l15 & 1) << 2) | quad) ^ ((l15 >> 1) & 7);
  int ra = ((wr << 5) + (l15 >> 1)) * 64 + cph * 8;   // + m*512 per 16-row frag
  int rb = ((wc << 5) + (l15 >> 1)) * 64 + cph * 8;   // + n*512

  // staging lane map (see header comment); wave stages rows 32wid..32wid+31
  int srl = lane >> 3;
  int clog = (lane & 7) ^ srl;
  int r_l = (srl << 1) | (clog >> 2);
  int q_l = clog & 3;
  const unsigned short* gA = A + (size_t)(slot0 + 32 * wid + r_l) * K + q_l * 8;
  const unsigned short* gB = Bp + (size_t)(n0 + 32 * wid + r_l) * K + q_l * 8;

#define STG(buf, kt) do {                                                \
    gld16(gA + (size_t)(kt) * 32, &lA[buf][(32 * wid) * 32]);            \
    gld16(gA + (size_t)16 * K + (size_t)(kt) * 32,                       \
          &lA[buf][(32 * wid + 16) * 32]);                               \
    gld16(gB + (size_t)(kt) * 32, &lB[buf][(32 * wid) * 32]);            \
    gld16(gB + (size_t)16 * K + (size_t)(kt) * 32,                       \
          &lB[buf][(32 * wid + 16) * 32]);                               \
  } while (0)
#define SYNC4 asm volatile("s_waitcnt vmcnt(4)\n\ts_barrier" ::: "memory")

  floatx4 acc[4][4];
#pragma unroll
  for (int mi = 0; mi < 4; mi++)
#pragma unroll
    for (int ni = 0; ni < 4; ni++) acc[mi][ni] = (floatx4){0.f, 0.f, 0.f, 0.f};

  constexpr int NK = K / 32;

  // prologue: stage K-steps 0,1; vmcnt(4) leaves step 1's group in flight
  STG(0, 0);
  STG(1, 1);
  SYNC4;

#define STEP(j, t) do {                                                  \
    int kt = ((t) + 2 < NK) ? (t) + 2 : 0;                               \
    STG(((j) + 2) % 3, kt);                                              \
    short8 af[4], bfr[4];                                                \
    _Pragma("unroll")                                                    \
    for (int m = 0; m < 4; m++) af[m] = *(const short8*)&lA[j][ra + m * 512]; \
    _Pragma("unroll")                                                    \
    for (int n = 0; n < 4; n++) bfr[n] = *(const short8*)&lB[j][rb + n * 512]; \
    _Pragma("unroll")                                                    \
    for (int m = 0; m < 4; m++)                                          \
      _Pragma("unroll")                                                  \
      for (int n = 0; n < 4; n++)                                        \
        acc[m][n] = __builtin_amdgcn_mfma_f32_16x16x32_bf16(af[m], bfr[n], acc[m][n], 0, 0, 0); \
    SYNC4;                                                               \
  } while (0)

  for (int t3 = 0; t3 < NK; t3 += 3) {
    STEP(0, t3);
    if (t3 + 1 < NK) STEP(1, t3 + 1);
    if (t3 + 2 < NK) STEP(2, t3 + 2);
  }
#undef STEP
#undef STG
#undef SYNC4

  const float* bias = bias_all + (size_t)e * N;
#pragma unroll
  for (int mi = 0; mi < 4; mi++) {
    int row = slot0 + 64 * wr + 16 * mi + quad * 4;
#pragma unroll
    for (int ni = 0; ni < 4; ni++) {
      int col = n0 + 64 * wc + 16 * ni + l15;
      float bv = bias[col];
#pragma unroll
      for (int r = 0; r < 4; r++) {
        float v = acc[mi][ni][r] + bv;
        if (GELU) v = gelu_f(v);
        O[(size_t)(row + r) * N + col] = f2bf(v);
      }
    }
  }
}

// ---- combine: out[t] = w0*Yg[pos(2t)] + w1*Yg[pos(2t+1)] ----
__global__ void combine_k(const unsigned short* __restrict__ Yg,
                          const int* __restrict__ pos_of,
                          const float* __restrict__ tw, float* __restrict__ out) {
  int t = blockIdx.x;
  int p0 = pos_of[2 * t], p1 = pos_of[2 * t + 1];
  float w0 = tw[2 * t], w1 = tw[2 * t + 1];
  uint2 a = ((const uint2*)(Yg + (size_t)p0 * D_))[threadIdx.x];
  uint2 b = ((const uint2*)(Yg + (size_t)p1 * D_))[threadIdx.x];
  float4 r;
  r.x = w0 * bf2f(a.x & 0xffffu) + w1 * bf2f(b.x & 0xffffu);
  r.y = w0 * bf2f(a.x >> 16)     + w1 * bf2f(b.x >> 16);
  r.z = w0 * bf2f(a.y & 0xffffu) + w1 * bf2f(b.y & 0xffffu);
  r.w = w0 * bf2f(a.y >> 16)     + w1 * bf2f(b.y >> 16);
  ((float4*)(out + (size_t)t * D_))[threadIdx.x] = r;
}

extern "C" void kernel_launch(void* const* d_in, const int* in_sizes, int n_in,
                              void* d_out, int out_size, void* d_ws, size_t ws_size,
                              hipStream_t stream) {
  const float* x  = (const float*)d_in[0];
  const float* gw = (const float*)d_in[1];
  const float* gb = (const float*)d_in[2];
  const float* w1 = (const float*)d_in[3];
  const float* b1 = (const float*)d_in[4];
  const float* w2 = (const float*)d_in[5];
  const float* b2 = (const float*)d_in[6];
  float* out = (float*)d_out;

  char* p = (char*)d_ws;
  unsigned short* w1t = (unsigned short*)p; p += (size_t)E_ * D_ * F_ * 2;
  unsigned short* w2t = (unsigned short*)p; p += (size_t)E_ * D_ * F_ * 2;
  unsigned short* Xg  = (unsigned short*)p; p += (size_t)CAP * D_ * 2;
  unsigned short* H   = (unsigned short*)p; p += (size_t)CAP * F_ * 2;
  int*   idx    = (int*)p; p += (size_t)CAP * 4;
  int*   pos_of = (int*)p; p += (size_t)NS * 4;
  int*   ti     = (int*)p; p += (size_t)NS * 4;
  float* tw     = (float*)p; p += (size_t)NS * 4;
  int* cursors = (int*)p; p += 64;
  int* offs    = (int*)p; p += 64;
  unsigned short* Yg = Xg;  // alias: Xg dead after gemm1, Yg born in gemm2

  dim3 tb(32, 8);
  transpose_cvt<<<dim3(F_ / 32, D_ / 32, E_), tb, 0, stream>>>(w1, w1t, D_, F_);
  transpose_cvt<<<dim3(D_ / 32, F_ / 32, E_), tb, 0, stream>>>(w2, w2t, F_, D_);
  router_k<<<NT / 4, 256, 0, stream>>>(x, gw, gb, ti, tw);
  count_prefix_k<<<1, 256, 0, stream>>>(ti, offs, cursors);
  scatter_k<<<NS / 256, 256, 0, stream>>>(ti, tw, cursors, idx, pos_of);
  gather_k<<<CAP, 256, 0, stream>>>(x, idx, Xg);
  gemm_k<D_, F_, true><<<dim3(F_ / 128, CAP / 128), 256, 0, stream>>>(Xg, w1t, b1, H, offs);
  gemm_k<F_, D_, false><<<dim3(D_ / 128, CAP / 128), 256, 0, stream>>>(H, w2t, b2, Yg, offs);
  combine_k<<<NT, 256, 0, stream>>>(Yg, pos_of, tw, out);
}

// Round 5
// 465.043 us; speedup vs baseline: 1.0954x; 1.0411x over previous
//
#include <hip/hip_runtime.h>
#include <hip/hip_bf16.h>
#include <math.h>

#define B_ 4
#define T_ 2048
#define D_ 1024
#define F_ 2048
#define E_ 8
#define NT (B_ * T_)          // 8192 tokens
#define NS (NT * 2)           // 16384 routed assignments (K=2)
#define CAP (NS + E_ * 128)   // 17408 slots: 128-aligned per-expert segments always fit

typedef __attribute__((ext_vector_type(8))) short short8;
typedef __attribute__((ext_vector_type(4))) float floatx4;

static __device__ __forceinline__ unsigned short f2bf(float f) {
  union { float f; unsigned u; } a; a.f = f;
  unsigned r = a.u + 0x7fffu + ((a.u >> 16) & 1u);  // RNE
  return (unsigned short)(r >> 16);
}

static __device__ __forceinline__ float bf2f(unsigned u) {
  union { unsigned u; float f; } a; a.u = u << 16; return a.f;
}

static __device__ __forceinline__ void gld16(const unsigned short* g, unsigned short* l) {
  __builtin_amdgcn_global_load_lds(
      (const __attribute__((address_space(1))) void*)g,
      (__attribute__((address_space(3))) void*)l, 16, 0, 0);
}

// Branchless GELU: Abramowitz-Stegun 7.1.26 erf (|err| < 1.5e-7), hw exp2/rcp.
static __device__ __forceinline__ float gelu_f(float v) {
  float ax = fabsf(v) * 0.70710678118654752f;
  float t = __builtin_amdgcn_rcpf(1.f + 0.3275911f * ax);
  float e = __builtin_amdgcn_exp2f(-ax * ax * 1.44269504088896f);  // exp(-ax^2)
  float p = t * (0.254829592f +
            t * (-0.284496736f +
            t * (1.421413741f +
            t * (-1.453152027f +
            t * 1.061405429f))));
  float er = 1.f - p * e;
  er = copysignf(er, v);
  return 0.5f * v * (1.f + er);
}

// ---- weight transpose + fp32->bf16 convert: in [E][R][C] -> out [E][C][R] ----
// 64x64 tile, 256 threads. Reads float4 coalesced (256B/row-segment), writes
// uint4 = 8 bf16 coalesced (128B per 8-lane group). LDS banks 2-way both sides
// (free). Replaces the 2B-scalar-store version (half-density write waves).
__global__ void transpose_cvt(const float* __restrict__ in, unsigned short* __restrict__ out,
                              int R, int C) {
  __shared__ float tile[64][65];
  int e = blockIdx.z;
  const float* inp = in + (size_t)e * R * C;
  unsigned short* outp = out + (size_t)e * R * C;
  int c0 = blockIdx.x * 64, r0 = blockIdx.y * 64;
  int tid = threadIdx.x;            // 256
  int rl = tid >> 4;                // 0..15
  int cl = (tid & 15) * 4;          // 0,4,..,60
#pragma unroll
  for (int jr = 0; jr < 4; jr++) {
    int row = rl + 16 * jr;
    float4 v = *(const float4*)&inp[(size_t)(r0 + row) * C + c0 + cl];
    tile[row][cl + 0] = v.x; tile[row][cl + 1] = v.y;
    tile[row][cl + 2] = v.z; tile[row][cl + 3] = v.w;
  }
  __syncthreads();
  int cc0 = tid >> 3;               // 0..31
  int rq = (tid & 7) * 8;           // 0,8,..,56
#pragma unroll
  for (int jc = 0; jc < 2; jc++) {
    int cc = cc0 + 32 * jc;
    unsigned w[4];
#pragma unroll
    for (int i = 0; i < 4; i++) {
      unsigned lo = f2bf(tile[rq + 2 * i][cc]);
      unsigned hi = f2bf(tile[rq + 2 * i + 1][cc]);
      w[i] = lo | (hi << 16);
    }
    *(uint4*)&outp[(size_t)(c0 + cc) * R + r0 + rq] = make_uint4(w[0], w[1], w[2], w[3]);
  }
}

// ---- router: fp32 logits, top-2, softmax over the pair. NO atomics. ----
__global__ void router_k(const float* __restrict__ x, const float* __restrict__ gw,
                         const float* __restrict__ gb, int* __restrict__ ti,
                         float* __restrict__ tw) {
  int wid = threadIdx.x >> 6, lane = threadIdx.x & 63;
  int t = blockIdx.x * 4 + wid;
  const float* xr = x + (size_t)t * D_;
  float acc[E_];
#pragma unroll
  for (int e = 0; e < E_; e++) acc[e] = 0.f;
#pragma unroll
  for (int it = 0; it < D_ / 64; it++) {
    int d = it * 64 + lane;
    float xv = xr[d];
    const float* g = gw + d * E_;
#pragma unroll
    for (int e = 0; e < E_; e++) acc[e] += xv * g[e];
  }
#pragma unroll
  for (int off = 32; off > 0; off >>= 1)
#pragma unroll
    for (int e = 0; e < E_; e++) acc[e] += __shfl_xor(acc[e], off);
  if (lane == 0) {
    float v[E_];
#pragma unroll
    for (int e = 0; e < E_; e++) v[e] = acc[e] + gb[e];
    int i0 = 0; float v0 = v[0];
#pragma unroll
    for (int e = 1; e < E_; e++) if (v[e] > v0) { v0 = v[e]; i0 = e; }
    int i1 = -1; float v1 = -3.4e38f;
#pragma unroll
    for (int e = 0; e < E_; e++) if (e != i0 && v[e] > v1) { v1 = v[e]; i1 = e; }
    float ex = expf(v1 - v0);           // <= 1, no overflow
    float w0 = 1.f / (1.f + ex);
    float w1 = ex / (1.f + ex);
    ti[2 * t] = i0; tw[2 * t] = w0;
    ti[2 * t + 1] = i1; tw[2 * t + 1] = w1;
  }
}

// ---- single-block histogram + 128-aligned exclusive prefix ----
__global__ void count_prefix_k(const int* __restrict__ ti, int* __restrict__ offs,
                               int* __restrict__ cursors) {
  __shared__ int scnt[4][E_];
  int tid = threadIdx.x;  // 256 threads
  int cnt[E_];
#pragma unroll
  for (int k = 0; k < E_; k++) cnt[k] = 0;
  for (int i = tid; i < NS; i += 256) {
    int e = ti[i];
#pragma unroll
    for (int k = 0; k < E_; k++) cnt[k] += (e == k) ? 1 : 0;
  }
#pragma unroll
  for (int off = 32; off > 0; off >>= 1)
#pragma unroll
    for (int k = 0; k < E_; k++) cnt[k] += __shfl_xor(cnt[k], off);
  int wid = tid >> 6, lane = tid & 63;
  if (lane == 0)
#pragma unroll
    for (int k = 0; k < E_; k++) scnt[wid][k] = cnt[k];
  __syncthreads();
  if (tid == 0) {
    int o = 0;
    for (int k = 0; k < E_; k++) {
      int c = scnt[0][k] + scnt[1][k] + scnt[2][k] + scnt[3][k];
      offs[k] = o;
      cursors[k] = o;
      o += (c + 127) & ~127;
    }
    offs[E_] = o;
  }
}

// ---- wave-aggregated scatter: 8 atomics per wave; records slot of each assignment ----
__global__ void scatter_k(const int* __restrict__ ti, const float* __restrict__ tw,
                          int* __restrict__ cursors, int* __restrict__ idx,
                          int* __restrict__ pos_of) {
  int a = blockIdx.x * 256 + threadIdx.x;  // 0..NS-1
  int lane = threadIdx.x & 63;
  int e = ti[a];
  unsigned long long m[E_];
#pragma unroll
  for (int k = 0; k < E_; k++) m[k] = __ballot(e == k);
  int base = 0;
  if (lane < E_) base = atomicAdd(&cursors[lane], __popcll(m[lane]));
  int myBase = __shfl(base, e);
  unsigned long long m_mine = 0;
#pragma unroll
  for (int k = 0; k < E_; k++) if (e == k) m_mine = m[k];
  int rank = __popcll(m_mine & ((1ull << lane) - 1ull));
  int pos = myBase + rank;
  idx[pos] = a >> 1;
  pos_of[a] = pos;
}

// ---- gather routed token rows into bf16, slot-major. Pad slots hold stale
// workspace garbage (no fill pass): clamp into [0,NT) — their outputs are
// never combined, so any in-bounds row is fine. ----
__global__ void gather_k(const float* __restrict__ x, const int* __restrict__ idx,
                         unsigned short* __restrict__ Xg) {
  int s = blockIdx.x;
  int t = idx[s];
  t = ((unsigned)t < (unsigned)NT) ? t : 0;
  const float4* xr = (const float4*)(x + (size_t)t * D_);
  float4 v = xr[threadIdx.x];
  uint2 p;
  p.x = (unsigned)f2bf(v.x) | ((unsigned)f2bf(v.y) << 16);
  p.y = (unsigned)f2bf(v.z) | ((unsigned)f2bf(v.w) << 16);
  ((uint2*)(Xg + (size_t)s * D_))[threadIdx.x] = p;
}

// ---- grouped GEMM: 128x128 tile, BK=32, 4 waves (2Mx2N), 3-buffer LDS
// rotation, counted vmcnt (never 0), one barrier per K-step.
// + XCD-aware swizzle (T1): hardware blockIdx round-robins across the 8 XCDs,
// so map h -> logical = (h&7)*(nwg/8) + h>>3 (bijective, nwg%8==0). Each XCD
// then owns 17 contiguous row-tiles x all col-tiles: blocks sharing an A-strip
// are co-resident on ONE XCD (L2 hit instead of 8x HBM re-fetch), per-expert W
// panels stay hot per-XCD, and the full working set (<=105 MB) is L3-resident.
// R4 measured 300 MB FETCH vs 105 MB compulsory on gemm2 -> this targets that.
//
// LDS swizzle (BK=32, 64-B rows, PMC-verified 0 conflicts): phys 16-B chunk of
// logical (row r, k-chunk q) = (((r&1)<<2)|q) ^ ((r>>1)&7) within each 128-B
// superrow-pair. Staging keeps LDS dest linear (gld16 requirement) and
// pre-permutes the per-lane GLOBAL source: lane i covers logical (r_l,q_l)
// with c = (i&7)^(i>>3), r_l = (i>>3)*2 + (c>>2), q_l = c&3.
//
// Ledger per wave: entering step t, outstanding = step t+1's 4 gld16; step t
// issues 4 for t+2 -> 8; vmcnt(4) before the barrier retires exactly t+1's
// group. Tail dummy-stages kt=0. Buffer indices compile-time (unroll by 3).
template <int K, int N, bool GELU>
__global__ __launch_bounds__(256, 3) void gemm_k(const unsigned short* __restrict__ A,
                                                 const unsigned short* __restrict__ W,
                                                 const float* __restrict__ bias_all,
                                                 unsigned short* __restrict__ O,
                                                 const int* __restrict__ offs) {
  constexpr int NC = N / 128;
  int h = blockIdx.x;
  int logical = (h & 7) * ((int)gridDim.x >> 3) + (h >> 3);
  int rt = logical / NC, ct = logical - rt * NC;   // NC is a power of 2
  int slot0 = rt * 128;
  if (slot0 >= offs[E_]) return;
  int e = 0;
  while (slot0 >= offs[e + 1]) e++;
  const unsigned short* Bp = W + (size_t)e * N * K;
  int n0 = ct * 128;

  __shared__ unsigned short lA[3][128 * 32];
  __shared__ unsigned short lB[3][128 * 32];

  int tid = threadIdx.x;
  int wid = tid >> 6, lane = tid & 63;
  int wr = wid >> 1, wc = wid & 1;          // 2M x 2N wave grid, per-wave out 64x64
  int quad = lane >> 4, l15 = lane & 15;

  // LDS read bases (shorts): row r = 16-aligned base + l15 -> (r>>1)&7 = (l15>>1)&7
  int cph = (((l15 & 1) << 2) | quad) ^ ((l15 >> 1) & 7);
  int ra = ((wr << 5) + (l15 >> 1)) * 64 + cph * 8;   // + m*512 per 16-row frag
  int rb = ((wc << 5) + (l15 >> 1)) * 64 + cph * 8;   // + n*512

  // staging lane map (see header comment); wave stages rows 32wid..32wid+31
  int srl = lane >> 3;
  int clog = (lane & 7) ^ srl;
  int r_l = (srl << 1) | (clog >> 2);
  int q_l = clog & 3;
  const unsigned short* gA = A + (size_t)(slot0 + 32 * wid + r_l) * K + q_l * 8;
  const unsigned short* gB = Bp + (size_t)(n0 + 32 * wid + r_l) * K + q_l * 8;

#define STG(buf, kt) do {                                                \
    gld16(gA + (size_t)(kt) * 32, &lA[buf][(32 * wid) * 32]);            \
    gld16(gA + (size_t)16 * K + (size_t)(kt) * 32,                       \
          &lA[buf][(32 * wid + 16) * 32]);                               \
    gld16(gB + (size_t)(kt) * 32, &lB[buf][(32 * wid) * 32]);            \
    gld16(gB + (size_t)16 * K + (size_t)(kt) * 32,                       \
          &lB[buf][(32 * wid + 16) * 32]);                               \
  } while (0)
#define SYNC4 asm volatile("s_waitcnt vmcnt(4)\n\ts_barrier" ::: "memory")

  floatx4 acc[4][4];
#pragma unroll
  for (int mi = 0; mi < 4; mi++)
#pragma unroll
    for (int ni = 0; ni < 4; ni++) acc[mi][ni] = (floatx4){0.f, 0.f, 0.f, 0.f};

  constexpr int NK = K / 32;

  // prologue: stage K-steps 0,1; vmcnt(4) leaves step 1's group in flight
  STG(0, 0);
  STG(1, 1);
  SYNC4;

#define STEP(j, t) do {                                                  \
    int kt = ((t) + 2 < NK) ? (t) + 2 : 0;                               \
    STG(((j) + 2) % 3, kt);                                              \
    short8 af[4], bfr[4];                                                \
    _Pragma("unroll")                                                    \
    for (int m = 0; m < 4; m++) af[m] = *(const short8*)&lA[j][ra + m * 512]; \
    _Pragma("unroll")                                                    \
    for (int n = 0; n < 4; n++) bfr[n] = *(const short8*)&lB[j][rb + n * 512]; \
    _Pragma("unroll")                                                    \
    for (int m = 0; m < 4; m++)                                          \
      _Pragma("unroll")                                                  \
      for (int n = 0; n < 4; n++)                                        \
        acc[m][n] = __builtin_amdgcn_mfma_f32_16x16x32_bf16(af[m], bfr[n], acc[m][n], 0, 0, 0); \
    SYNC4;                                                               \
  } while (0)

  for (int t3 = 0; t3 < NK; t3 += 3) {
    STEP(0, t3);
    if (t3 + 1 < NK) STEP(1, t3 + 1);
    if (t3 + 2 < NK) STEP(2, t3 + 2);
  }
#undef STEP
#undef STG
#undef SYNC4

  const float* bias = bias_all + (size_t)e * N;
#pragma unroll
  for (int mi = 0; mi < 4; mi++) {
    int row = slot0 + 64 * wr + 16 * mi + quad * 4;
#pragma unroll
    for (int ni = 0; ni < 4; ni++) {
      int col = n0 + 64 * wc + 16 * ni + l15;
      float bv = bias[col];
#pragma unroll
      for (int r = 0; r < 4; r++) {
        float v = acc[mi][ni][r] + bv;
        if (GELU) v = gelu_f(v);
        O[(size_t)(row + r) * N + col] = f2bf(v);
      }
    }
  }
}

// ---- combine: out[t] = w0*Yg[pos(2t)] + w1*Yg[pos(2t+1)] ----
__global__ void combine_k(const unsigned short* __restrict__ Yg,
                          const int* __restrict__ pos_of,
                          const float* __restrict__ tw, float* __restrict__ out) {
  int t = blockIdx.x;
  int p0 = pos_of[2 * t], p1 = pos_of[2 * t + 1];
  float w0 = tw[2 * t], w1 = tw[2 * t + 1];
  uint2 a = ((const uint2*)(Yg + (size_t)p0 * D_))[threadIdx.x];
  uint2 b = ((const uint2*)(Yg + (size_t)p1 * D_))[threadIdx.x];
  float4 r;
  r.x = w0 * bf2f(a.x & 0xffffu) + w1 * bf2f(b.x & 0xffffu);
  r.y = w0 * bf2f(a.x >> 16)     + w1 * bf2f(b.x >> 16);
  r.z = w0 * bf2f(a.y & 0xffffu) + w1 * bf2f(b.y & 0xffffu);
  r.w = w0 * bf2f(a.y >> 16)     + w1 * bf2f(b.y >> 16);
  ((float4*)(out + (size_t)t * D_))[threadIdx.x] = r;
}

extern "C" void kernel_launch(void* const* d_in, const int* in_sizes, int n_in,
                              void* d_out, int out_size, void* d_ws, size_t ws_size,
                              hipStream_t stream) {
  const float* x  = (const float*)d_in[0];
  const float* gw = (const float*)d_in[1];
  const float* gb = (const float*)d_in[2];
  const float* w1 = (const float*)d_in[3];
  const float* b1 = (const float*)d_in[4];
  const float* w2 = (const float*)d_in[5];
  const float* b2 = (const float*)d_in[6];
  float* out = (float*)d_out;

  char* p = (char*)d_ws;
  unsigned short* w1t = (unsigned short*)p; p += (size_t)E_ * D_ * F_ * 2;
  unsigned short* w2t = (unsigned short*)p; p += (size_t)E_ * D_ * F_ * 2;
  unsigned short* Xg  = (unsigned short*)p; p += (size_t)CAP * D_ * 2;
  unsigned short* H   = (unsigned short*)p; p += (size_t)CAP * F_ * 2;
  int*   idx    = (int*)p; p += (size_t)CAP * 4;
  int*   pos_of = (int*)p; p += (size_t)NS * 4;
  int*   ti     = (int*)p; p += (size_t)NS * 4;
  float* tw     = (float*)p; p += (size_t)NS * 4;
  int* cursors = (int*)p; p += 64;
  int* offs    = (int*)p; p += 64;
  unsigned short* Yg = Xg;  // alias: Xg dead after gemm1, Yg born in gemm2

  transpose_cvt<<<dim3(F_ / 64, D_ / 64, E_), 256, 0, stream>>>(w1, w1t, D_, F_);
  transpose_cvt<<<dim3(D_ / 64, F_ / 64, E_), 256, 0, stream>>>(w2, w2t, F_, D_);
  router_k<<<NT / 4, 256, 0, stream>>>(x, gw, gb, ti, tw);
  count_prefix_k<<<1, 256, 0, stream>>>(ti, offs, cursors);
  scatter_k<<<NS / 256, 256, 0, stream>>>(ti, tw, cursors, idx, pos_of);
  gather_k<<<CAP, 256, 0, stream>>>(x, idx, Xg);
  gemm_k<D_, F_, true><<<dim3((CAP / 128) * (F_ / 128)), 256, 0, stream>>>(Xg, w1t, b1, H, offs);
  gemm_k<F_, D_, false><<<dim3((CAP / 128) * (D_ / 128)), 256, 0, stream>>>(H, w2t, b2, Yg, offs);
  combine_k<<<NT, 256, 0, stream>>>(Yg, pos_of, tw, out);
}